// Round 4
// baseline (61349.109 us; speedup 1.0000x reference)
//
#include <hip/hip_runtime.h>
#include <cstddef>

#define DEV __device__ __forceinline__

// ---- dims: B=16 S=256 IN_DIM=264 H=512 4H=2048 XI=471 N=256 M=64 R=4 OUT=256
constexpr int S_ = 256;
constexpr int NB = 256;
constexpr int NT = 256;

// ---- ws float offsets ----
constexpr size_t OFF_H    = 0;         // 16x512
constexpr size_t OFF_C    = 8192;      // 2x16x512 ping-pong
constexpr size_t OFF_MEM  = 24576;     // 16x256x64
constexpr size_t OFF_NRM  = 286720;    // 16x256
constexpr size_t OFF_USG  = 290816;    // 16x256
constexpr size_t OFF_LNK  = 294912;    // 16x256x256
constexpr size_t OFF_PRC  = 1343488;   // 2x16x256 ping-pong
constexpr size_t OFF_WR   = 1351680;   // 16x4x256
constexpr size_t OFF_WW   = 1368064;   // 16x256
constexpr size_t OFF_RV   = 1372160;   // 16x256
constexpr size_t OFF_XI   = 1376256;   // 16x480
constexpr size_t OFF_KNR  = 1383936;   // 16x256
constexpr size_t OFF_PI   = 1388032;   // 16x16
constexpr size_t OFF_ERS  = 1388288;   // 16x64
constexpr size_t OFF_WVC  = 1389312;   // 16x64
constexpr size_t OFF_FWD  = 1390336;   // 16x4x256
constexpr size_t OFF_BWD  = 1406720;   // 16x4x256
constexpr size_t OFF_ALC  = 1423104;   // 16x256
constexpr size_t OFF_CW   = 1427200;   // 16x256
constexpr size_t OFF_SCL  = 1431296;   // 16x4 (g_a, g_w, sumAlloc)
constexpr size_t OFF_GPX  = 1431360;   // 16x2048 gates partial: x
constexpr size_t OFF_GPH  = 1464128;   // 16x2048 gates partial: h
constexpr size_t OFF_GPRV = 1496896;   // 16x2048 gates partial: rv
constexpr size_t OFF_YH   = 1529664;   // 16x256  h@Wy + by
constexpr size_t OFF_FLG  = 1533824;   // 256 arrival flags, 1 per 128B line (32 u32 stride)
constexpr size_t OFF_REL  = 1542016;   // 16 replicated release lines (32 u32 stride)
constexpr size_t WS_TOTAL = 1542528;   // ~6.17 MB

DEV float sigm(float x){ return 1.0f/(1.0f+expf(-x)); }
DEV float oneplus_(float x){ float sp = (x>20.0f)? x : log1pf(expf(x)); return 1.0f+sp; }

DEV float wredsum(float v){
  #pragma unroll
  for (int o=32;o>0;o>>=1) v += __shfl_xor(v,o);
  return v;
}
DEV float wredmax(float v){
  #pragma unroll
  for (int o=32;o>0;o>>=1) v = fmaxf(v,__shfl_xor(v,o));
  return v;
}
DEV float bredsum(float v, float* red){
  v = wredsum(v);
  if ((threadIdx.x&63)==0) red[threadIdx.x>>6]=v;
  __syncthreads();
  float r = red[0]+red[1]+red[2]+red[3];
  __syncthreads();
  return r;
}
DEV float bredmax(float v, float* red){
  v = wredmax(v);
  if ((threadIdx.x&63)==0) red[threadIdx.x>>6]=v;
  __syncthreads();
  float r = fmaxf(fmaxf(red[0],red[1]),fmaxf(red[2],red[3]));
  __syncthreads();
  return r;
}

// Grid barrier, 256 co-resident blocks (grid == CU count).
// R2 post-mortem: AGENT-scope spin reads hit stale (non-coherent) per-XCD L2
// -> ~85us/barrier (eviction timescale). R3 post-mortem: SYSTEM-scope fixed
// visibility but kept a single shared atomicAdd counter: 256 same-line RMWs
// serialize at the LLC at ~175ns each -> ~45us/barrier of pure arrival
// serialization (VALUBusy 2.3%).
// This version is contention-free:
//   arrivals : each block STOREs epoch to its own 128B-line flag (no RMW,
//              all 256 in parallel)
//   detect   : wave 0 of block 0 sweeps the 256 flags (4 loads/lane)
//   release  : master stores epoch to 16 replicated lines; block b polls
//              line b>>4 (<=16 same-line pollers) with s_sleep backoff.
// Fences identical to the R3-verified pattern (release wbL2 before flag,
// acquire inv after release observed).
DEV void gbar(unsigned* flg, unsigned* rel, unsigned ep, int bid){
  __syncthreads();
  const int tid = threadIdx.x;
  if (bid == 0){
    if (tid == 0){
      __threadfence();
      __hip_atomic_store(flg, ep, __ATOMIC_RELAXED, __HIP_MEMORY_SCOPE_SYSTEM);
    }
    if (tid < 64){
      bool ok;
      do {
        ok = true;
        #pragma unroll
        for (int s=0;s<4;++s){
          unsigned v = __hip_atomic_load(flg + (size_t)(tid + (s<<6))*32,
                                         __ATOMIC_RELAXED, __HIP_MEMORY_SCOPE_SYSTEM);
          ok = ok && (v >= ep);
        }
      } while (!__all(ok));
      if (tid == 0) __threadfence();
      if (tid < 16){
        __hip_atomic_store(rel + (size_t)tid*32, ep,
                           __ATOMIC_RELAXED, __HIP_MEMORY_SCOPE_SYSTEM);
      }
      if (tid == 0) __threadfence();
    }
  } else {
    if (tid == 0){
      __threadfence();
      __hip_atomic_store(flg + (size_t)bid*32, ep,
                         __ATOMIC_RELAXED, __HIP_MEMORY_SCOPE_SYSTEM);
      unsigned* myrel = rel + (size_t)(bid>>4)*32;
      while (__hip_atomic_load(myrel, __ATOMIC_RELAXED, __HIP_MEMORY_SCOPE_SYSTEM) < ep)
        __builtin_amdgcn_s_sleep(2);
      __threadfence();
    }
  }
  __syncthreads();
}

// skinny GEMM: 32 cols x 16 batches, in-block 8-way ksplit.
// sx: LDS activations [k][20] (b fastest). W row-major ldw. colx = this thread's col.
// partials land in sred[ks*512 + b*32 + col].
DEV void sgemm_core(float* sred, const float* sx, const float* __restrict__ W,
                    int ldw, int colx, int kn)
{
  const int tid = threadIdx.x;
  const int ks  = tid >> 5;
  const int k0  = ks * kn;
  float acc[16];
  #pragma unroll
  for (int i=0;i<16;++i) acc[i]=0.f;
  const float* wp = W + (size_t)k0*ldw + colx;
  const float* xp = sx + k0*20;
  #pragma unroll 4
  for (int k=0;k<kn;++k){
    float w = *wp; wp += ldw;
    float4 x0 = *(const float4*)(xp);
    float4 x1 = *(const float4*)(xp+4);
    float4 x2 = *(const float4*)(xp+8);
    float4 x3 = *(const float4*)(xp+12);
    xp += 20;
    acc[0]=fmaf(w,x0.x,acc[0]);  acc[1]=fmaf(w,x0.y,acc[1]);
    acc[2]=fmaf(w,x0.z,acc[2]);  acc[3]=fmaf(w,x0.w,acc[3]);
    acc[4]=fmaf(w,x1.x,acc[4]);  acc[5]=fmaf(w,x1.y,acc[5]);
    acc[6]=fmaf(w,x1.z,acc[6]);  acc[7]=fmaf(w,x1.w,acc[7]);
    acc[8]=fmaf(w,x2.x,acc[8]);  acc[9]=fmaf(w,x2.y,acc[9]);
    acc[10]=fmaf(w,x2.z,acc[10]); acc[11]=fmaf(w,x2.w,acc[11]);
    acc[12]=fmaf(w,x3.x,acc[12]); acc[13]=fmaf(w,x3.y,acc[13]);
    acc[14]=fmaf(w,x3.z,acc[14]); acc[15]=fmaf(w,x3.w,acc[15]);
  }
  const int col = tid & 31;
  #pragma unroll
  for (int b=0;b<16;++b) sred[ks*512 + b*32 + col] = acc[b];
}

#define SRED8(o) (sred[(o)]+sred[512+(o)]+sred[1024+(o)]+sred[1536+(o)]+ \
                  sred[2048+(o)]+sred[2560+(o)]+sred[3072+(o)]+sred[3584+(o)])

DEV void stage_x264(float* sx, const float* __restrict__ xin, int tt){
  for (int e=threadIdx.x; e<4224; e+=NT){
    int b = e/264, k = e - b*264;
    sx[k*20+b] = xin[((size_t)(b*256+tt))*264 + k];
  }
}
DEV void stage_h(float* sx, const float* h){
  for (int e=threadIdx.x; e<8192; e+=NT){
    int b = e>>9, k = e&511;
    sx[k*20+b] = h[(b<<9)+k];
  }
}
DEV void stage_rv(float* sx, const float* rv){
  for (int e=threadIdx.x; e<4096; e+=NT){
    int b = e>>8, k = e&255;
    sx[k*20+b] = rv[(b<<8)+k];
  }
}

__global__ void k_zero(float* __restrict__ ws){
  size_t i = (size_t)blockIdx.x*blockDim.x + threadIdx.x;
  size_t st = (size_t)gridDim.x*blockDim.x;
  for (; i<WS_TOTAL; i+=st) ws[i]=0.0f;
}

__global__ __launch_bounds__(NT, 2) void k_dnc(
    const float* __restrict__ xin, const float* __restrict__ Wx,
    const float* __restrict__ Wh,  const float* __restrict__ bl,
    const float* __restrict__ Wxi, const float* __restrict__ bxi,
    const float* __restrict__ Wy,  const float* __restrict__ Wr,
    const float* __restrict__ by,  float* __restrict__ out,
    float* __restrict__ ws)
{
  __shared__ float smem[14336];   // 57.3 KB: sx(10240) + sred(4096) union w/ per-phase overlays
  float* sx   = smem;
  float* sred = smem + 10240;
  const int tid  = threadIdx.x;
  const int bid  = blockIdx.x;
  const int lane = tid & 63, wv = tid >> 6;
  unsigned* flg = (unsigned*)(ws + OFF_FLG);
  unsigned* rel = (unsigned*)(ws + OFF_REL);
  unsigned ep = 0;

  // ---- prologue: gates x-part for t=0 ----
  if (bid < 64){
    stage_x264(sx, xin, 0);
    __syncthreads();
    sgemm_core(sred, sx, Wx, 2048, (bid<<5)+(tid&31), 33);
    __syncthreads();
    for (int o=tid;o<512;o+=NT){
      int b=o>>5, c=o&31;
      ws[OFF_GPX+(size_t)(b<<11)+(bid<<5)+c] = SRED8(o);
    }
  }
  ep++; gbar(flg, rel, ep, bid);

  for (int t=0; t<S_; ++t){
    // ================= phase B: LSTM + xi + yh =================
    if (bid < 24){
      const float* gpx = ws+OFF_GPX; const float* gph = ws+OFF_GPH; const float* gprv = ws+OFF_GPRV;
      const float* cold = ws+OFF_C + (size_t)(t&1)*8192;
      for (int i=0;i<32;++i){
        int e = tid + (i<<8);
        int b = e>>9, j = e&511;
        size_t g0 = (size_t)(b<<11) + j;
        float gi = gpx[g0]     +gph[g0]     +gprv[g0]     +bl[j];
        float gf = gpx[g0+512] +gph[g0+512] +gprv[g0+512] +bl[512+j];
        float gg = gpx[g0+1024]+gph[g0+1024]+gprv[g0+1024]+bl[1024+j];
        float go = gpx[g0+1536]+gph[g0+1536]+gprv[g0+1536]+bl[1536+j];
        float cn = sigm(gf)*cold[(b<<9)+j] + sigm(gi)*tanhf(gg);
        sx[j*20+b] = sigm(go)*tanhf(cn);
      }
      __syncthreads();
      if (bid < 16){
        int cbase = bid<<5;
        int cc = cbase + (tid&31);
        sgemm_core(sred, sx, Wxi, 471, (cc<471?cc:470), 64);
        __syncthreads();
        for (int o=tid;o<512;o+=NT){
          int b=o>>5, c=o&31; int col=cbase+c;
          if (col<471) ws[OFF_XI + b*480 + col] = SRED8(o) + bxi[col];
        }
      } else {
        int cbase = (bid-16)<<5;
        sgemm_core(sred, sx, Wy, 256, cbase+(tid&31), 64);
        __syncthreads();
        for (int o=tid;o<512;o+=NT){
          int b=o>>5, c=o&31;
          ws[OFF_YH + (b<<8) + cbase + c] = SRED8(o) + by[cbase+c];
        }
      }
    } else if (bid < 28){
      const float* gpx = ws+OFF_GPX; const float* gph = ws+OFF_GPH; const float* gprv = ws+OFF_GPRV;
      const float* cold = ws+OFF_C + (size_t)(t&1)*8192;
      float* cnew = ws+OFF_C + (size_t)((t+1)&1)*8192;
      float* hg = ws+OFF_H;
      for (int i=0;i<8;++i){
        int e = ((bid-24)<<11) + tid + (i<<8);
        int b = e>>9, j = e&511;
        size_t g0 = (size_t)(b<<11) + j;
        float gi = gpx[g0]     +gph[g0]     +gprv[g0]     +bl[j];
        float gf = gpx[g0+512] +gph[g0+512] +gprv[g0+512] +bl[512+j];
        float gg = gpx[g0+1024]+gph[g0+1024]+gprv[g0+1024]+bl[1024+j];
        float go = gpx[g0+1536]+gph[g0+1536]+gprv[g0+1536]+bl[1536+j];
        float cn = sigm(gf)*cold[(b<<9)+j] + sigm(gi)*tanhf(gg);
        cnew[(b<<9)+j] = cn;
        hg[(b<<9)+j] = sigm(go)*tanhf(cn);
      }
    }
    ep++; gbar(flg, rel, ep, bid);

    // ====== phase C: ctrl/sort | write-content softmax | gates-x(t+1) ======
    if (bid < 16){
      int b = bid;
      float* xv = smem; float* uu = smem+512; float* sa = smem+768; float* sb = smem+1024; float* red = smem+1280;
      for (int e=tid;e<480;e+=NT) xv[e]=ws[OFF_XI+b*480+e];
      __syncthreads();
      int n = tid;
      float f0=sigm(xv[453]), f1=sigm(xv[454]), f2=sigm(xv[455]), f3=sigm(xv[456]);
      const float* wrb = ws+OFF_WR+(size_t)(b<<10);
      float psi=(1.f-f0*wrb[n])*(1.f-f1*wrb[256+n])*(1.f-f2*wrb[512+n])*(1.f-f3*wrb[768+n]);
      float uo=ws[OFF_USG+(b<<8)+n], wwp=ws[OFF_WW+(b<<8)+n];
      float un=(uo+wwp-uo*wwp)*psi;
      uu[n]=un; ws[OFF_USG+(b<<8)+n]=un;
      __syncthreads();
      int rk=0;
      #pragma unroll 8
      for (int j=0;j<256;++j){
        float uj=uu[j];
        rk += (uj<un)||(uj==un && j<n);
      }
      sa[rk]=un;
      __syncthreads();
      float* cur=sa; float* nxt=sb;
      for (int off=1;off<256;off<<=1){
        float v=cur[n]; if (n>=off) v*=cur[n-off];
        nxt[n]=v;
        __syncthreads();
        float* tmp=cur; cur=nxt; nxt=tmp;
      }
      float pe = rk ? cur[rk-1] : 1.f;
      float al = (1.f-un)*pe;
      ws[OFF_ALC+(b<<8)+n]=al;
      float sumA = bredsum(al, red);
      if (tid==0){
        ws[OFF_SCL+b*4+0]=sigm(xv[457]);
        ws[OFF_SCL+b*4+1]=sigm(xv[458]);
        ws[OFF_SCL+b*4+2]=sumA;
      }
      {
        int r=tid>>6, m=tid&63;
        float kv=xv[(r<<6)+m];
        float s2=wredsum(kv*kv);
        float br=oneplus_(xv[256+r]);
        ws[OFF_KNR+(b<<8)+tid]=kv*br/(sqrtf(s2)+1e-6f);
      }
      if (tid<4){
        float p0=xv[459+tid*3], p1=xv[460+tid*3], p2=xv[461+tid*3];
        float mx=fmaxf(p0,fmaxf(p1,p2));
        float e0=expf(p0-mx), e1=expf(p1-mx), e2=expf(p2-mx);
        float s=e0+e1+e2;
        float* pg=ws+OFF_PI+b*16+tid*3;
        pg[0]=e0/s; pg[1]=e1/s; pg[2]=e2/s;
      }
      if (tid<64){
        ws[OFF_ERS+(b<<6)+tid]=sigm(xv[325+tid]);
        ws[OFF_WVC+(b<<6)+tid]=xv[389+tid];
      }
      float* bw=ws+OFF_BWD+(size_t)(b<<10);
      bw[tid]=0.f; bw[256+tid]=0.f; bw[512+tid]=0.f; bw[768+tid]=0.f;
    } else if (bid < 32){
      int b = bid-16;
      float* knw=smem; float* sims=smem+64; float* red=smem+320;
      if (wv==0){
        float kv=ws[OFF_XI+b*480+260+lane];
        float s2=wredsum(kv*kv);
        float bw_=oneplus_(ws[OFF_XI+b*480+324]);
        knw[lane]=kv*bw_/(sqrtf(s2)+1e-6f);
      }
      __syncthreads();
      const float* memb=ws+OFF_MEM+(size_t)b*16384;
      for (int it=0;it<64;++it){
        int n=(wv<<6)+it;
        float v=memb[(n<<6)+lane];
        float d=wredsum(v*knw[lane]);
        if (lane==0) sims[n]=d/(sqrtf(ws[OFF_NRM+(b<<8)+n])+1e-6f);
      }
      __syncthreads();
      float s=sims[tid];
      float mx=bredmax(s,red); float e=expf(s-mx); float sm=bredsum(e,red);
      ws[OFF_CW+(b<<8)+tid]=e/sm;
    } else if (bid < 96){
      if (t < 255){
        stage_x264(sx, xin, t+1);
        __syncthreads();
        sgemm_core(sred, sx, Wx, 2048, ((bid-32)<<5)+(tid&31), 33);
        __syncthreads();
        for (int o=tid;o<512;o+=NT){
          int b=o>>5, c=o&31;
          ws[OFF_GPX+(size_t)(b<<11)+((bid-32)<<5)+c] = SRED8(o);
        }
      }
    }
    ep++; gbar(flg, rel, ep, bid);

    // ================= phase D: link + fwd/bwd | mem + nrm + prec =================
    if (bid < 128){
      int b=bid>>3, rc=bid&7;
      float* wwi=smem; float* wrl=smem+32; float* fpart=smem+160; // 32,128,512
      float ga=ws[OFF_SCL+b*4], gw=ws[OFF_SCL+b*4+1];
      int j=tid;
      float wj=gw*(ga*ws[OFF_ALC+(b<<8)+j]+(1.f-ga)*ws[OFF_CW+(b<<8)+j]);
      float pj=ws[OFF_PRC+(size_t)(t&1)*4096+(b<<8)+j];
      const float* wrb=ws+OFF_WR+(size_t)(b<<10);
      float wr0=wrb[j], wr1=wrb[256+j], wr2=wrb[512+j], wr3=wrb[768+j];
      if (tid<32){
        int i=(rc<<5)+tid;
        wwi[tid]=gw*(ga*ws[OFF_ALC+(b<<8)+i]+(1.f-ga)*ws[OFF_CW+(b<<8)+i]);
      }
      if (tid<128) wrl[(tid>>5)*32+(tid&31)] = wrb[((tid>>5)<<8)+(rc<<5)+(tid&31)];
      __syncthreads();
      float b0=0.f,b1=0.f,b2=0.f,b3=0.f;
      float* lrow=ws+OFF_LNK+(size_t)b*65536+(size_t)(rc<<5)*256;
      for (int il=0;il<32;++il){
        int i=(rc<<5)+il;
        float Lo=lrow[il*256+j];
        float wi=wwi[il];
        float Ln=(1.f-wi-wj)*Lo + wi*pj;
        if (i==j) Ln=0.f;
        lrow[il*256+j]=Ln;
        float s0=wredsum(Ln*wr0), s1=wredsum(Ln*wr1), s2=wredsum(Ln*wr2), s3=wredsum(Ln*wr3);
        if (lane==0){
          fpart[wv*128+il]=s0; fpart[wv*128+32+il]=s1;
          fpart[wv*128+64+il]=s2; fpart[wv*128+96+il]=s3;
        }
        b0=fmaf(Ln,wrl[il],b0); b1=fmaf(Ln,wrl[32+il],b1);
        b2=fmaf(Ln,wrl[64+il],b2); b3=fmaf(Ln,wrl[96+il],b3);
      }
      __syncthreads();
      if (tid<128){
        int r=tid>>5, il=tid&31;
        float s=fpart[r*32+il]+fpart[128+r*32+il]+fpart[256+r*32+il]+fpart[384+r*32+il];
        ws[OFF_FWD+(size_t)(b<<10)+(r<<8)+(rc<<5)+il]=s;
      }
      float* bwd=ws+OFF_BWD+(size_t)(b<<10);
      atomicAdd(&bwd[j],b0); atomicAdd(&bwd[256+j],b1);
      atomicAdd(&bwd[512+j],b2); atomicAdd(&bwd[768+j],b3);
    } else if (bid < 144){
      int b=bid-128;
      float ga=ws[OFF_SCL+b*4], gw=ws[OFF_SCL+b*4+1], sA=ws[OFF_SCL+b*4+2];
      float sww=gw*(ga*sA+(1.f-ga));
      float er=ws[OFF_ERS+(b<<6)+lane], wvv=ws[OFF_WVC+(b<<6)+lane];
      float* memb=ws+OFF_MEM+(size_t)b*16384;
      for (int it=0;it<64;++it){
        int n=(wv<<6)+it;
        float wwn=gw*(ga*ws[OFF_ALC+(b<<8)+n]+(1.f-ga)*ws[OFF_CW+(b<<8)+n]);
        float v=memb[(n<<6)+lane];
        v=v*(1.f-wwn*er)+wwn*wvv;
        memb[(n<<6)+lane]=v;
        float s2=wredsum(v*v);
        if (lane==0){
          ws[OFF_NRM+(b<<8)+n]=s2;
          ws[OFF_WW +(b<<8)+n]=wwn;
          float po=ws[OFF_PRC+(size_t)(t&1)*4096+(b<<8)+n];
          ws[OFF_PRC+(size_t)((t+1)&1)*4096+(b<<8)+n]=(1.f-sww)*po+wwn;
        }
      }
    }
    ep++; gbar(flg, rel, ep, bid);

    // ================= phase E: read heads | gates-h(t+1) =================
    if (bid < 64){
      int b=bid>>2, r=bid&3;
      float* knl=smem; float* sims=smem+64; float* wrs=smem+320; float* part=smem+576; float* red=smem+832;
      if (wv==0) knl[lane]=ws[OFF_KNR+(b<<8)+(r<<6)+lane];
      __syncthreads();
      const float* memb=ws+OFF_MEM+(size_t)b*16384;
      for (int it=0;it<64;++it){
        int n=(wv<<6)+it;
        float v=memb[(n<<6)+lane];
        float d=wredsum(v*knl[lane]);
        if (lane==0) sims[n]=d/(sqrtf(ws[OFF_NRM+(b<<8)+n])+1e-6f);
      }
      __syncthreads();
      float s=sims[tid];
      float mx=bredmax(s,red); float e=expf(s-mx); float sm=bredsum(e,red);
      float cr=e/sm;
      float p0=ws[OFF_PI+b*16+r*3], p1=ws[OFF_PI+b*16+r*3+1], p2=ws[OFF_PI+b*16+r*3+2];
      float wr=p0*ws[OFF_BWD+(size_t)(b<<10)+(r<<8)+tid] + p1*cr
             + p2*ws[OFF_FWD+(size_t)(b<<10)+(r<<8)+tid];
      ws[OFF_WR+(size_t)(b<<10)+(r<<8)+tid]=wr;
      wrs[tid]=wr;
      __syncthreads();
      float acc=0.f;
      for (int it=0;it<64;++it){
        int n=(wv<<6)+it;
        acc=fmaf(wrs[n],memb[(n<<6)+lane],acc);
      }
      part[(wv<<6)+lane]=acc;
      __syncthreads();
      if (tid<64) ws[OFF_RV+(b<<8)+(r<<6)+tid]=part[tid]+part[64+tid]+part[128+tid]+part[192+tid];
    } else if (bid < 128){
      if (t < 255){
        stage_h(sx, ws+OFF_H);
        __syncthreads();
        sgemm_core(sred, sx, Wh, 2048, ((bid-64)<<5)+(tid&31), 64);
        __syncthreads();
        for (int o=tid;o<512;o+=NT){
          int b=o>>5, c=o&31;
          ws[OFF_GPH+(size_t)(b<<11)+((bid-64)<<5)+c] = SRED8(o);
        }
      }
    }
    ep++; gbar(flg, rel, ep, bid);

    // ============ phase A': gates-rv(t+1) | y output (step t) ============
    if (bid < 64){
      if (t < 255){
        stage_rv(sx, ws+OFF_RV);
        __syncthreads();
        sgemm_core(sred, sx, Wx+(size_t)264*2048, 2048, (bid<<5)+(tid&31), 32);
        __syncthreads();
        for (int o=tid;o<512;o+=NT){
          int b=o>>5, c=o&31;
          ws[OFF_GPRV+(size_t)(b<<11)+(bid<<5)+c] = SRED8(o);
        }
      }
    } else if (bid < 72){
      stage_rv(sx, ws+OFF_RV);
      __syncthreads();
      int cbase=(bid-64)<<5;
      sgemm_core(sred, sx, Wr, 256, cbase+(tid&31), 32);
      __syncthreads();
      for (int o=tid;o<512;o+=NT){
        int b=o>>5, c=o&31;
        out[((size_t)((b<<8)+t)<<8)+cbase+c] = ws[OFF_YH+(b<<8)+cbase+c] + SRED8(o);
      }
    }
    ep++; gbar(flg, rel, ep, bid);
  }
}

extern "C" void kernel_launch(void* const* d_in, const int* in_sizes, int n_in,
                              void* d_out, int out_size, void* d_ws, size_t ws_size,
                              hipStream_t stream) {
  (void)in_sizes; (void)out_size;
  if (n_in < 9) return;
  const float* xin = (const float*)d_in[0];
  const float* Wx  = (const float*)d_in[1];
  const float* Wh  = (const float*)d_in[2];
  const float* bl  = (const float*)d_in[3];
  const float* Wxi = (const float*)d_in[4];
  const float* bxi = (const float*)d_in[5];
  const float* Wy  = (const float*)d_in[6];
  const float* Wr  = (const float*)d_in[7];
  const float* by  = (const float*)d_in[8];
  float* out = (float*)d_out;
  float* ws  = (float*)d_ws;
  if (ws_size < WS_TOTAL*sizeof(float)) return;

  hipLaunchKernelGGL(k_zero, dim3(512), dim3(256), 0, stream, ws);
  hipLaunchKernelGGL(k_dnc, dim3(NB), dim3(NT), 0, stream,
                     xin, Wx, Wh, bl, Wxi, bxi, Wy, Wr, by, out, ws);
}

// Round 5
// 60099.170 us; speedup vs baseline: 1.0208x; 1.0208x over previous
//
#include <hip/hip_runtime.h>
#include <cstddef>

#define DEV __device__ __forceinline__

// ---- dims: B=16 S=256 IN_DIM=264 H=512 4H=2048 XI=471 N=256 M=64 R=4 OUT=256
constexpr int S_ = 256;
constexpr int NB = 256;
constexpr int NT = 256;

// ---- ws float offsets ----
// Coherence plan (R4 post-mortem): NO __threadfence anywhere -> no buffer_wbl2/
// buffer_inv (the ~45us/barrier full-L2 tag-walk that dominated R1..R4).
// Cross-block-shared state is accessed ONLY via relaxed SYSTEM-scope atomics
// (sc0 sc1: bypass L1/L2, read/write the LLC directly). Block-private state
// (LNK slices: same block every step; weights/xin: read-only) stays cached in
// L2 and is never invalidated -> warm for all 256 steps.
constexpr size_t OFF_H    = 0;         // 16x512              [sys]
constexpr size_t OFF_C    = 8192;      // 2x16x512 ping-pong  [sys]
constexpr size_t OFF_MEM  = 24576;     // 16x256x64           [sys]
constexpr size_t OFF_NRM  = 286720;    // 16x256              [sys]
constexpr size_t OFF_USG  = 290816;    // 16x256              [private cached]
constexpr size_t OFF_LNK  = 294912;    // 16x256x256          [private cached]
constexpr size_t OFF_PRC  = 1343488;   // 2x16x256 ping-pong  [sys]
constexpr size_t OFF_WR   = 1351680;   // 16x4x256            [sys]
constexpr size_t OFF_WW   = 1368064;   // 16x256              [sys]
constexpr size_t OFF_RV   = 1372160;   // 16x256              [sys]
constexpr size_t OFF_XI   = 1376256;   // 16x480              [sys]
constexpr size_t OFF_KNR  = 1383936;   // 16x256              [sys]
constexpr size_t OFF_PI   = 1388032;   // 16x16               [sys]
constexpr size_t OFF_ERS  = 1388288;   // 16x64               [sys]
constexpr size_t OFF_WVC  = 1389312;   // 16x64               [sys]
constexpr size_t OFF_FWD  = 1390336;   // 16x4x256            [sys]
constexpr size_t OFF_BWD  = 1406720;   // 16x4x256            [atomic+sys]
constexpr size_t OFF_ALC  = 1423104;   // 16x256              [sys]
constexpr size_t OFF_CW   = 1427200;   // 16x256              [sys]
constexpr size_t OFF_SCL  = 1431296;   // 16x4                [sys]
constexpr size_t OFF_GP   = 1431360;   // 16x2048 gates accum: C stores x-part,
                                       // E atomicAdd h-part, A' atomicAdd rv-part
constexpr size_t OFF_YH   = 1464128;   // 16x256  h@Wy + by   [sys]
constexpr size_t OFF_FLG  = 1468224;   // 256 arrival flags, 1/128B line
constexpr size_t OFF_REL  = 1476416;   // 16 replicated release lines
constexpr size_t WS_TOTAL = 1476928;   // ~5.9 MB

DEV float ldg_sys(const float* p){
  return __hip_atomic_load((float*)p, __ATOMIC_RELAXED, __HIP_MEMORY_SCOPE_SYSTEM);
}
DEV void stg_sys(float* p, float v){
  __hip_atomic_store(p, v, __ATOMIC_RELAXED, __HIP_MEMORY_SCOPE_SYSTEM);
}

DEV float sigm(float x){ return 1.0f/(1.0f+expf(-x)); }
DEV float oneplus_(float x){ float sp = (x>20.0f)? x : log1pf(expf(x)); return 1.0f+sp; }

DEV float wredsum(float v){
  #pragma unroll
  for (int o=32;o>0;o>>=1) v += __shfl_xor(v,o);
  return v;
}
DEV float wredmax(float v){
  #pragma unroll
  for (int o=32;o>0;o>>=1) v = fmaxf(v,__shfl_xor(v,o));
  return v;
}
DEV float bredsum(float v, float* red){
  v = wredsum(v);
  if ((threadIdx.x&63)==0) red[threadIdx.x>>6]=v;
  __syncthreads();
  float r = red[0]+red[1]+red[2]+red[3];
  __syncthreads();
  return r;
}
DEV float bredmax(float v, float* red){
  v = wredmax(v);
  if ((threadIdx.x&63)==0) red[threadIdx.x>>6]=v;
  __syncthreads();
  float r = fmaxf(fmaxf(red[0],red[1]),fmaxf(red[2],red[3]));
  __syncthreads();
  return r;
}

// Grid barrier, 256 co-resident blocks. FENCE-FREE:
// - all cross-visible data is written with sc0sc1 stores (straight to LLC);
// - __syncthreads() emits s_waitcnt vmcnt(0) per wave (HIP semantics), so by
//   the time thread0 runs, every store of this block is LLC-visible;
// - arrival = relaxed sys store to own 128B line; master (block 0, wave 0)
//   sweeps 256 flags; release = 16 replicated lines, <=16 pollers each.
// No __threadfence -> no buffer_wbl2/buffer_inv -> no full-L2 flush.
DEV void gbar(unsigned* flg, unsigned* rel, unsigned ep, int bid){
  __syncthreads();
  const int tid = threadIdx.x;
  if (bid == 0){
    if (tid == 0)
      __hip_atomic_store(flg, ep, __ATOMIC_RELAXED, __HIP_MEMORY_SCOPE_SYSTEM);
    if (tid < 64){
      bool ok;
      do {
        ok = true;
        #pragma unroll
        for (int s=0;s<4;++s){
          unsigned v = __hip_atomic_load(flg + (size_t)(tid + (s<<6))*32,
                                         __ATOMIC_RELAXED, __HIP_MEMORY_SCOPE_SYSTEM);
          ok = ok && (v >= ep);
        }
        if (!__all(ok)) __builtin_amdgcn_s_sleep(1);
      } while (!__all(ok));
      if (tid < 16)
        __hip_atomic_store(rel + (size_t)tid*32, ep,
                           __ATOMIC_RELAXED, __HIP_MEMORY_SCOPE_SYSTEM);
    }
  } else {
    if (tid == 0){
      __hip_atomic_store(flg + (size_t)bid*32, ep,
                         __ATOMIC_RELAXED, __HIP_MEMORY_SCOPE_SYSTEM);
      unsigned* myrel = rel + (size_t)(bid>>4)*32;
      while (__hip_atomic_load(myrel, __ATOMIC_RELAXED, __HIP_MEMORY_SCOPE_SYSTEM) < ep)
        __builtin_amdgcn_s_sleep(2);
    }
  }
  __syncthreads();
}

// skinny GEMM: 32 cols x 16 batches, in-block 8-way ksplit.
// sx: LDS activations [k][20]. W row-major (cached, read-only -> L2-warm).
DEV void sgemm_core(float* sred, const float* sx, const float* __restrict__ W,
                    int ldw, int colx, int kn)
{
  const int tid = threadIdx.x;
  const int ks  = tid >> 5;
  const int k0  = ks * kn;
  float acc[16];
  #pragma unroll
  for (int i=0;i<16;++i) acc[i]=0.f;
  const float* wp = W + (size_t)k0*ldw + colx;
  const float* xp = sx + k0*20;
  #pragma unroll 4
  for (int k=0;k<kn;++k){
    float w = *wp; wp += ldw;
    float4 x0 = *(const float4*)(xp);
    float4 x1 = *(const float4*)(xp+4);
    float4 x2 = *(const float4*)(xp+8);
    float4 x3 = *(const float4*)(xp+12);
    xp += 20;
    acc[0]=fmaf(w,x0.x,acc[0]);  acc[1]=fmaf(w,x0.y,acc[1]);
    acc[2]=fmaf(w,x0.z,acc[2]);  acc[3]=fmaf(w,x0.w,acc[3]);
    acc[4]=fmaf(w,x1.x,acc[4]);  acc[5]=fmaf(w,x1.y,acc[5]);
    acc[6]=fmaf(w,x1.z,acc[6]);  acc[7]=fmaf(w,x1.w,acc[7]);
    acc[8]=fmaf(w,x2.x,acc[8]);  acc[9]=fmaf(w,x2.y,acc[9]);
    acc[10]=fmaf(w,x2.z,acc[10]); acc[11]=fmaf(w,x2.w,acc[11]);
    acc[12]=fmaf(w,x3.x,acc[12]); acc[13]=fmaf(w,x3.y,acc[13]);
    acc[14]=fmaf(w,x3.z,acc[14]); acc[15]=fmaf(w,x3.w,acc[15]);
  }
  const int col = tid & 31;
  #pragma unroll
  for (int b=0;b<16;++b) sred[ks*512 + b*32 + col] = acc[b];
}

#define SRED8(o) (sred[(o)]+sred[512+(o)]+sred[1024+(o)]+sred[1536+(o)]+ \
                  sred[2048+(o)]+sred[2560+(o)]+sred[3072+(o)]+sred[3584+(o)])

DEV void stage_x264(float* sx, const float* __restrict__ xin, int tt){
  for (int e=threadIdx.x; e<4224; e+=NT){
    int b = e/264, k = e - b*264;
    sx[k*20+b] = xin[((size_t)(b*256+tt))*264 + k];   // read-only: cached
  }
}
DEV void stage_h_sys(float* sx, const float* h){
  for (int e=threadIdx.x; e<8192; e+=NT){
    int b = e>>9, k = e&511;
    sx[k*20+b] = ldg_sys(h + (b<<9) + k);
  }
}
DEV void stage_rv_sys(float* sx, const float* rv){
  for (int e=threadIdx.x; e<4096; e+=NT){
    int b = e>>8, k = e&255;
    sx[k*20+b] = ldg_sys(rv + (b<<8) + k);
  }
}

__global__ void k_zero(float* __restrict__ ws){
  size_t i = (size_t)blockIdx.x*blockDim.x + threadIdx.x;
  size_t st = (size_t)gridDim.x*blockDim.x;
  for (; i<WS_TOTAL; i+=st) ws[i]=0.0f;
}

__global__ __launch_bounds__(NT, 2) void k_dnc(
    const float* __restrict__ xin, const float* __restrict__ Wx,
    const float* __restrict__ Wh,  const float* __restrict__ bl,
    const float* __restrict__ Wxi, const float* __restrict__ bxi,
    const float* __restrict__ Wy,  const float* __restrict__ Wr,
    const float* __restrict__ by,  float* __restrict__ out,
    float* __restrict__ ws)
{
  __shared__ float smem[14336];
  float* sx   = smem;
  float* sred = smem + 10240;
  const int tid  = threadIdx.x;
  const int bid  = blockIdx.x;
  const int lane = tid & 63, wv = tid >> 6;
  unsigned* flg = (unsigned*)(ws + OFF_FLG);
  unsigned* rel = (unsigned*)(ws + OFF_REL);
  unsigned ep = 0;

  // ---- prologue: gates x-part for t=0 (h0=rv0=0 -> GP = x-part only) ----
  if (bid < 64){
    stage_x264(sx, xin, 0);
    __syncthreads();
    sgemm_core(sred, sx, Wx, 2048, (bid<<5)+(tid&31), 33);
    __syncthreads();
    for (int o=tid;o<512;o+=NT){
      int b=o>>5, c=o&31;
      stg_sys(ws + OFF_GP + (size_t)(b<<11) + (bid<<5) + c, SRED8(o));
    }
  }
  ep++; gbar(flg, rel, ep, bid);

  for (int t=0; t<S_; ++t){
    // ================= phase B: LSTM + xi + yh =================
    if (bid < 24){
      const float* gp = ws+OFF_GP;
      const float* cold = ws+OFF_C + (size_t)(t&1)*8192;
      for (int i=0;i<32;++i){
        int e = tid + (i<<8);
        int b = e>>9, j = e&511;
        size_t g0 = (size_t)(b<<11) + j;
        float gi = ldg_sys(gp+g0)      + bl[j];
        float gf = ldg_sys(gp+g0+512)  + bl[512+j];
        float gg = ldg_sys(gp+g0+1024) + bl[1024+j];
        float go = ldg_sys(gp+g0+1536) + bl[1536+j];
        float cn = sigm(gf)*ldg_sys(cold+(b<<9)+j) + sigm(gi)*tanhf(gg);
        sx[j*20+b] = sigm(go)*tanhf(cn);
      }
      __syncthreads();
      if (bid < 16){
        int cbase = bid<<5;
        int cc = cbase + (tid&31);
        sgemm_core(sred, sx, Wxi, 471, (cc<471?cc:470), 64);
        __syncthreads();
        for (int o=tid;o<512;o+=NT){
          int b=o>>5, c=o&31; int col=cbase+c;
          if (col<471) stg_sys(ws + OFF_XI + (size_t)b*480 + col, SRED8(o) + bxi[col]);
        }
      } else {
        int cbase = (bid-16)<<5;
        sgemm_core(sred, sx, Wy, 256, cbase+(tid&31), 64);
        __syncthreads();
        for (int o=tid;o<512;o+=NT){
          int b=o>>5, c=o&31;
          stg_sys(ws + OFF_YH + (b<<8) + cbase + c, SRED8(o) + by[cbase+c]);
        }
      }
    } else if (bid < 28){
      const float* gp = ws+OFF_GP;
      const float* cold = ws+OFF_C + (size_t)(t&1)*8192;
      float* cnew = ws+OFF_C + (size_t)((t+1)&1)*8192;
      float* hg = ws+OFF_H;
      for (int i=0;i<8;++i){
        int e = ((bid-24)<<11) + tid + (i<<8);
        int b = e>>9, j = e&511;
        size_t g0 = (size_t)(b<<11) + j;
        float gi = ldg_sys(gp+g0)      + bl[j];
        float gf = ldg_sys(gp+g0+512)  + bl[512+j];
        float gg = ldg_sys(gp+g0+1024) + bl[1024+j];
        float go = ldg_sys(gp+g0+1536) + bl[1536+j];
        float cn = sigm(gf)*ldg_sys(cold+(b<<9)+j) + sigm(gi)*tanhf(gg);
        stg_sys(cnew+(b<<9)+j, cn);
        stg_sys(hg+(b<<9)+j, sigm(go)*tanhf(cn));
      }
    }
    ep++; gbar(flg, rel, ep, bid);

    // ====== phase C: ctrl/sort | write-content softmax | gates-x(t+1) ======
    if (bid < 16){
      int b = bid;
      float* xv = smem; float* uu = smem+512; float* sa = smem+768; float* sb = smem+1024; float* red = smem+1280;
      for (int e=tid;e<480;e+=NT) xv[e]=ldg_sys(ws+OFF_XI+(size_t)b*480+e);
      __syncthreads();
      int n = tid;
      float f0=sigm(xv[453]), f1=sigm(xv[454]), f2=sigm(xv[455]), f3=sigm(xv[456]);
      const float* wrb = ws+OFF_WR+(size_t)(b<<10);
      float psi=(1.f-f0*ldg_sys(wrb+n))*(1.f-f1*ldg_sys(wrb+256+n))
               *(1.f-f2*ldg_sys(wrb+512+n))*(1.f-f3*ldg_sys(wrb+768+n));
      float uo=ws[OFF_USG+(b<<8)+n];            // private cached
      float wwp=ldg_sys(ws+OFF_WW+(b<<8)+n);
      float un=(uo+wwp-uo*wwp)*psi;
      uu[n]=un; ws[OFF_USG+(b<<8)+n]=un;        // private cached
      __syncthreads();
      int rk=0;
      #pragma unroll 8
      for (int j=0;j<256;++j){
        float uj=uu[j];
        rk += (uj<un)||(uj==un && j<n);
      }
      sa[rk]=un;
      __syncthreads();
      float* cur=sa; float* nxt=sb;
      for (int off=1;off<256;off<<=1){
        float v=cur[n]; if (n>=off) v*=cur[n-off];
        nxt[n]=v;
        __syncthreads();
        float* tmp=cur; cur=nxt; nxt=tmp;
      }
      float pe = rk ? cur[rk-1] : 1.f;
      float al = (1.f-un)*pe;
      stg_sys(ws+OFF_ALC+(b<<8)+n, al);
      float sumA = bredsum(al, red);
      if (tid==0){
        stg_sys(ws+OFF_SCL+b*4+0, sigm(xv[457]));
        stg_sys(ws+OFF_SCL+b*4+1, sigm(xv[458]));
        stg_sys(ws+OFF_SCL+b*4+2, sumA);
      }
      {
        int r=tid>>6, m=tid&63;
        float kv=xv[(r<<6)+m];
        float s2=wredsum(kv*kv);
        float br=oneplus_(xv[256+r]);
        stg_sys(ws+OFF_KNR+(b<<8)+tid, kv*br/(sqrtf(s2)+1e-6f));
      }
      if (tid<4){
        float p0=xv[459+tid*3], p1=xv[460+tid*3], p2=xv[461+tid*3];
        float mx=fmaxf(p0,fmaxf(p1,p2));
        float e0=expf(p0-mx), e1=expf(p1-mx), e2=expf(p2-mx);
        float s=e0+e1+e2;
        stg_sys(ws+OFF_PI+b*16+tid*3+0, e0/s);
        stg_sys(ws+OFF_PI+b*16+tid*3+1, e1/s);
        stg_sys(ws+OFF_PI+b*16+tid*3+2, e2/s);
      }
      if (tid<64){
        stg_sys(ws+OFF_ERS+(b<<6)+tid, sigm(xv[325+tid]));
        stg_sys(ws+OFF_WVC+(b<<6)+tid, xv[389+tid]);
      }
      float* bw=ws+OFF_BWD+(size_t)(b<<10);
      stg_sys(bw+tid,0.f); stg_sys(bw+256+tid,0.f);
      stg_sys(bw+512+tid,0.f); stg_sys(bw+768+tid,0.f);
    } else if (bid < 32){
      int b = bid-16;
      float* knw=smem; float* sims=smem+64; float* red=smem+320;
      if (wv==0){
        float kv=ldg_sys(ws+OFF_XI+(size_t)b*480+260+lane);
        float s2=wredsum(kv*kv);
        float bw_=oneplus_(ldg_sys(ws+OFF_XI+(size_t)b*480+324));
        knw[lane]=kv*bw_/(sqrtf(s2)+1e-6f);
      }
      __syncthreads();
      const float* memb=ws+OFF_MEM+(size_t)b*16384;
      for (int it=0;it<64;++it){
        int n=(wv<<6)+it;
        float v=ldg_sys(memb+(n<<6)+lane);
        float d=wredsum(v*knw[lane]);
        if (lane==0) sims[n]=d/(sqrtf(ldg_sys(ws+OFF_NRM+(b<<8)+n))+1e-6f);
      }
      __syncthreads();
      float s=sims[tid];
      float mx=bredmax(s,red); float e=expf(s-mx); float sm=bredsum(e,red);
      stg_sys(ws+OFF_CW+(b<<8)+tid, e/sm);
    } else if (bid < 96){
      if (t < 255){
        stage_x264(sx, xin, t+1);
        __syncthreads();
        sgemm_core(sred, sx, Wx, 2048, ((bid-32)<<5)+(tid&31), 33);
        __syncthreads();
        for (int o=tid;o<512;o+=NT){
          int b=o>>5, c=o&31;
          stg_sys(ws + OFF_GP + (size_t)(b<<11) + ((bid-32)<<5) + c, SRED8(o));
        }
      }
    }
    ep++; gbar(flg, rel, ep, bid);

    // ================= phase D: link + fwd/bwd | mem + nrm + prec =================
    if (bid < 128){
      int b=bid>>3, rc=bid&7;
      float* wwi=smem; float* wrl=smem+32; float* fpart=smem+160;
      float ga=ldg_sys(ws+OFF_SCL+b*4), gw=ldg_sys(ws+OFF_SCL+b*4+1);
      int j=tid;
      float wj=gw*(ga*ldg_sys(ws+OFF_ALC+(b<<8)+j)+(1.f-ga)*ldg_sys(ws+OFF_CW+(b<<8)+j));
      float pj=ldg_sys(ws+OFF_PRC+(size_t)(t&1)*4096+(b<<8)+j);
      const float* wrb=ws+OFF_WR+(size_t)(b<<10);
      float wr0=ldg_sys(wrb+j), wr1=ldg_sys(wrb+256+j),
            wr2=ldg_sys(wrb+512+j), wr3=ldg_sys(wrb+768+j);
      if (tid<32){
        int i=(rc<<5)+tid;
        wwi[tid]=gw*(ga*ldg_sys(ws+OFF_ALC+(b<<8)+i)+(1.f-ga)*ldg_sys(ws+OFF_CW+(b<<8)+i));
      }
      if (tid<128) wrl[(tid>>5)*32+(tid&31)] = ldg_sys(wrb+((tid>>5)<<8)+(rc<<5)+(tid&31));
      __syncthreads();
      float b0=0.f,b1=0.f,b2=0.f,b3=0.f;
      float* lrow=ws+OFF_LNK+(size_t)b*65536+(size_t)(rc<<5)*256;   // PRIVATE: cached, L2-warm
      for (int il=0;il<32;++il){
        int i=(rc<<5)+il;
        float Lo=lrow[il*256+j];
        float wi=wwi[il];
        float Ln=(1.f-wi-wj)*Lo + wi*pj;
        if (i==j) Ln=0.f;
        lrow[il*256+j]=Ln;
        float s0=wredsum(Ln*wr0), s1=wredsum(Ln*wr1), s2=wredsum(Ln*wr2), s3=wredsum(Ln*wr3);
        if (lane==0){
          fpart[wv*128+il]=s0; fpart[wv*128+32+il]=s1;
          fpart[wv*128+64+il]=s2; fpart[wv*128+96+il]=s3;
        }
        b0=fmaf(Ln,wrl[il],b0); b1=fmaf(Ln,wrl[32+il],b1);
        b2=fmaf(Ln,wrl[64+il],b2); b3=fmaf(Ln,wrl[96+il],b3);
      }
      __syncthreads();
      if (tid<128){
        int r=tid>>5, il=tid&31;
        float s=fpart[r*32+il]+fpart[128+r*32+il]+fpart[256+r*32+il]+fpart[384+r*32+il];
        stg_sys(ws+OFF_FWD+(size_t)(b<<10)+(r<<8)+(rc<<5)+il, s);
      }
      float* bwd=ws+OFF_BWD+(size_t)(b<<10);   // agent atomics execute at LLC
      atomicAdd(&bwd[j],b0); atomicAdd(&bwd[256+j],b1);
      atomicAdd(&bwd[512+j],b2); atomicAdd(&bwd[768+j],b3);
    } else if (bid < 144){
      int b=bid-128;
      float ga=ldg_sys(ws+OFF_SCL+b*4), gw=ldg_sys(ws+OFF_SCL+b*4+1), sA=ldg_sys(ws+OFF_SCL+b*4+2);
      float sww=gw*(ga*sA+(1.f-ga));
      float er=ldg_sys(ws+OFF_ERS+(b<<6)+lane), wvv=ldg_sys(ws+OFF_WVC+(b<<6)+lane);
      float* memb=ws+OFF_MEM+(size_t)b*16384;
      for (int it=0;it<16;++it){
        int n=((wv<<4)+it)|0; n = (wv<<6>>2)*4; // (placeholder removed below)
      }
      for (int it=0;it<64;++it){
        int n=(wv<<6)+it;
        if (n>=256) break;
      }
      // 4 waves x 64 rows: wave wv handles rows wv*64..wv*64+63
      for (int it=0;it<64;++it){
        int n=(wv<<6)+it;
        float wwn=gw*(ga*ldg_sys(ws+OFF_ALC+(b<<8)+n)+(1.f-ga)*ldg_sys(ws+OFF_CW+(b<<8)+n));
        float v=ldg_sys(memb+(n<<6)+lane);
        v=v*(1.f-wwn*er)+wwn*wvv;
        stg_sys(memb+(n<<6)+lane, v);
        float s2=wredsum(v*v);
        if (lane==0){
          stg_sys(ws+OFF_NRM+(b<<8)+n, s2);
          stg_sys(ws+OFF_WW +(b<<8)+n, wwn);
          float po=ldg_sys(ws+OFF_PRC+(size_t)(t&1)*4096+(b<<8)+n);
          stg_sys(ws+OFF_PRC+(size_t)((t+1)&1)*4096+(b<<8)+n, (1.f-sww)*po+wwn);
        }
      }
    }
    ep++; gbar(flg, rel, ep, bid);

    // ================= phase E: read heads | gates-h(t+1) =================
    if (bid < 64){
      int b=bid>>2, r=bid&3;
      float* knl=smem; float* sims=smem+64; float* wrs=smem+320; float* part=smem+576; float* red=smem+832;
      if (wv==0) knl[lane]=ldg_sys(ws+OFF_KNR+(b<<8)+(r<<6)+lane);
      __syncthreads();
      const float* memb=ws+OFF_MEM+(size_t)b*16384;
      for (int it=0;it<64;++it){
        int n=(wv<<6)+it;
        float v=ldg_sys(memb+(n<<6)+lane);
        float d=wredsum(v*knl[lane]);
        if (lane==0) sims[n]=d/(sqrtf(ldg_sys(ws+OFF_NRM+(b<<8)+n))+1e-6f);
      }
      __syncthreads();
      float s=sims[tid];
      float mx=bredmax(s,red); float e=expf(s-mx); float sm=bredsum(e,red);
      float cr=e/sm;
      float p0=ldg_sys(ws+OFF_PI+b*16+r*3), p1=ldg_sys(ws+OFF_PI+b*16+r*3+1), p2=ldg_sys(ws+OFF_PI+b*16+r*3+2);
      float wr=p0*ldg_sys(ws+OFF_BWD+(size_t)(b<<10)+(r<<8)+tid) + p1*cr
             + p2*ldg_sys(ws+OFF_FWD+(size_t)(b<<10)+(r<<8)+tid);
      stg_sys(ws+OFF_WR+(size_t)(b<<10)+(r<<8)+tid, wr);
      wrs[tid]=wr;
      __syncthreads();
      float acc=0.f;
      for (int it=0;it<64;++it){
        int n=(wv<<6)+it;
        acc=fmaf(wrs[n],ldg_sys(memb+(n<<6)+lane),acc);
      }
      part[(wv<<6)+lane]=acc;
      __syncthreads();
      if (tid<64) stg_sys(ws+OFF_RV+(b<<8)+(r<<6)+tid,
                          part[tid]+part[64+tid]+part[128+tid]+part[192+tid]);
    } else if (bid < 128){
      if (t < 255){
        stage_h_sys(sx, ws+OFF_H);
        __syncthreads();
        sgemm_core(sred, sx, Wh, 2048, ((bid-64)<<5)+(tid&31), 64);
        __syncthreads();
        for (int o=tid;o<512;o+=NT){
          int b=o>>5, c=o&31;
          atomicAdd(ws + OFF_GP + (size_t)(b<<11) + ((bid-64)<<5) + c, SRED8(o));
        }
      }
    }
    ep++; gbar(flg, rel, ep, bid);

    // ============ phase A': gates-rv(t+1) | y output (step t) ============
    if (bid < 64){
      if (t < 255){
        stage_rv_sys(sx, ws+OFF_RV);
        __syncthreads();
        sgemm_core(sred, sx, Wx+(size_t)264*2048, 2048, (bid<<5)+(tid&31), 32);
        __syncthreads();
        for (int o=tid;o<512;o+=NT){
          int b=o>>5, c=o&31;
          atomicAdd(ws + OFF_GP + (size_t)(b<<11) + (bid<<5) + c, SRED8(o));
        }
      }
    } else if (bid < 72){
      stage_rv_sys(sx, ws+OFF_RV);
      __syncthreads();
      int cbase=(bid-64)<<5;
      sgemm_core(sred, sx, Wr, 256, cbase+(tid&31), 32);
      __syncthreads();
      for (int o=tid;o<512;o+=NT){
        int b=o>>5, c=o&31;
        out[((size_t)((b<<8)+t)<<8)+cbase+c] = ldg_sys(ws+OFF_YH+(b<<8)+cbase+c) + SRED8(o);
      }
    }
    ep++; gbar(flg, rel, ep, bid);
  }
}

extern "C" void kernel_launch(void* const* d_in, const int* in_sizes, int n_in,
                              void* d_out, int out_size, void* d_ws, size_t ws_size,
                              hipStream_t stream) {
  (void)in_sizes; (void)out_size;
  if (n_in < 9) return;
  const float* xin = (const float*)d_in[0];
  const float* Wx  = (const float*)d_in[1];
  const float* Wh  = (const float*)d_in[2];
  const float* bl  = (const float*)d_in[3];
  const float* Wxi = (const float*)d_in[4];
  const float* bxi = (const float*)d_in[5];
  const float* Wy  = (const float*)d_in[6];
  const float* Wr  = (const float*)d_in[7];
  const float* by  = (const float*)d_in[8];
  float* out = (float*)d_out;
  float* ws  = (float*)d_ws;
  if (ws_size < WS_TOTAL*sizeof(float)) return;

  hipLaunchKernelGGL(k_zero, dim3(512), dim3(256), 0, stream, ws);
  hipLaunchKernelGGL(k_dnc, dim3(NB), dim3(NT), 0, stream,
                     xin, Wx, Wh, bl, Wxi, bxi, Wy, Wr, by, out, ws);
}

// Round 6
// 28507.855 us; speedup vs baseline: 2.1520x; 2.1082x over previous
//
#include <hip/hip_runtime.h>
#include <cstddef>

#define DEV __device__ __forceinline__

// ---- dims: B=16 S=256 IN_DIM=264 H=512 4H=2048 XI=471 N=256 M=64 R=4 OUT=256
constexpr int S_ = 256;
constexpr int NB = 256;
constexpr int NT = 256;

// R5 post-mortem: bottleneck = straggler blocks issuing 10^4..10^5 scalar 4B
// high-latency loads (~250 outstanding/CU * 300-450ns). Fix: 64-bit accesses,
// redistribute redundant loads, and XCD-pin mem[] traffic (bid%8==b%8) so it
// runs AGENT-scope at the local L2 (~100ns) instead of SYSTEM at LLC.
// Coherence rules: a datum is either LLC-routed (sys everywhere: writers+readers),
// XCD-pinned (agent everywhere, all touching blocks on same XCD), or
// block-private/read-only (plain cached). Never mixed.
constexpr size_t OFF_H    = 0;         // 16x512   [sys]
constexpr size_t OFF_C    = 8192;      // 16x512   [private: B1 block b]
constexpr size_t OFF_MEM  = 24576;     // 16x256x64 [agent, XCD b%8]
constexpr size_t OFF_NRM  = 286720;    // 16x256   [agent, XCD b%8]
constexpr size_t OFF_USG  = 290816;    // 16x256   [private: ctrl block b]
constexpr size_t OFF_LNK  = 294912;    // 16x256x256 [private: link block]
constexpr size_t OFF_PRC  = 1343488;   // 2x16x256 [sys]
constexpr size_t OFF_WR   = 1351680;   // 16x4x256 [sys]
constexpr size_t OFF_WW   = 1368064;   // 16x256   [sys]
constexpr size_t OFF_RV   = 1372160;   // 16x256   [sys]
constexpr size_t OFF_XI   = 1376256;   // 16x480   [sys]
constexpr size_t OFF_KNR  = 1383936;   // 16x256   [agent, XCD b%8]
constexpr size_t OFF_PI   = 1388032;   // 16x16    [agent, XCD b%8]
constexpr size_t OFF_ERS  = 1388288;   // 16x64    [agent, XCD b%8]
constexpr size_t OFF_WVC  = 1389312;   // 16x64    [agent, XCD b%8]
constexpr size_t OFF_FWD  = 1390336;   // 16x4x256 [sys]
constexpr size_t OFF_BWD  = 1406720;   // 16x4x256 [sys zero + device atomicAdd]
constexpr size_t OFF_ALC  = 1423104;   // 16x256   [sys]
constexpr size_t OFF_CW   = 1427200;   // 16x256   [sys]
constexpr size_t OFF_SCL  = 1431296;   // 16x4     [sys]
constexpr size_t OFF_GPA  = 1431360;   // 16x2048 gates accum ping (t even)
constexpr size_t OFF_GPB  = 1464128;   // 16x2048 gates accum pong (t odd)
constexpr size_t OFF_YH   = 1496896;   // 16x256   [sys]
constexpr size_t OFF_FLG  = 1500992;   // 256 arrival flags, 1/128B line
constexpr size_t OFF_REL  = 1509184;   // 16 replicated release lines
constexpr size_t WS_TOTAL = 1509696;   // ~6.04 MB (R1 proved ws >= 6.25 MB)

typedef unsigned long long u64_;
union F2U { u64_ u; float2 f; };
DEV float2 ld2_sys(const float* p){ F2U c; c.u=__hip_atomic_load((const u64_*)p,__ATOMIC_RELAXED,__HIP_MEMORY_SCOPE_SYSTEM); return c.f; }
DEV void   st2_sys(float* p, float2 v){ F2U c; c.f=v; __hip_atomic_store((u64_*)p,c.u,__ATOMIC_RELAXED,__HIP_MEMORY_SCOPE_SYSTEM); }
DEV float2 ld2_agt(const float* p){ F2U c; c.u=__hip_atomic_load((const u64_*)p,__ATOMIC_RELAXED,__HIP_MEMORY_SCOPE_AGENT); return c.f; }
DEV void   st2_agt(float* p, float2 v){ F2U c; c.f=v; __hip_atomic_store((u64_*)p,c.u,__ATOMIC_RELAXED,__HIP_MEMORY_SCOPE_AGENT); }
DEV float  ld_sys(const float* p){ return __hip_atomic_load((float*)p,__ATOMIC_RELAXED,__HIP_MEMORY_SCOPE_SYSTEM); }
DEV void   st_sys(float* p,float v){ __hip_atomic_store(p,v,__ATOMIC_RELAXED,__HIP_MEMORY_SCOPE_SYSTEM); }
DEV float  ld_agt(const float* p){ return __hip_atomic_load((float*)p,__ATOMIC_RELAXED,__HIP_MEMORY_SCOPE_AGENT); }
DEV void   st_agt(float* p,float v){ __hip_atomic_store(p,v,__ATOMIC_RELAXED,__HIP_MEMORY_SCOPE_AGENT); }

DEV float sigm(float x){ return 1.0f/(1.0f+expf(-x)); }
DEV float oneplus_(float x){ float sp = (x>20.0f)? x : log1pf(expf(x)); return 1.0f+sp; }

DEV float wredsum(float v){
  #pragma unroll
  for (int o=32;o>0;o>>=1) v += __shfl_xor(v,o);
  return v;
}
DEV float hredsum32(float v){   // sum within each 32-lane half of the wave
  #pragma unroll
  for (int o=16;o>0;o>>=1) v += __shfl_xor(v,o);
  return v;
}
DEV float wredmax(float v){
  #pragma unroll
  for (int o=32;o>0;o>>=1) v = fmaxf(v,__shfl_xor(v,o));
  return v;
}
DEV float bredsum(float v, float* red){
  v = wredsum(v);
  if ((threadIdx.x&63)==0) red[threadIdx.x>>6]=v;
  __syncthreads();
  float r = red[0]+red[1]+red[2]+red[3];
  __syncthreads();
  return r;
}
DEV float bredmax(float v, float* red){
  v = wredmax(v);
  if ((threadIdx.x&63)==0) red[threadIdx.x>>6]=v;
  __syncthreads();
  float r = fmaxf(fmaxf(red[0],red[1]),fmaxf(red[2],red[3]));
  __syncthreads();
  return r;
}

// Fence-free grid barrier (R4/R5-proven). Arrival: own-line sys store.
// Master (block 0 wave 0) sweeps 256 flags; release via 16 replicated lines.
DEV void gbar(unsigned* flg, unsigned* rel, unsigned ep, int bid){
  __syncthreads();
  const int tid = threadIdx.x;
  if (bid == 0){
    if (tid == 0)
      __hip_atomic_store(flg, ep, __ATOMIC_RELAXED, __HIP_MEMORY_SCOPE_SYSTEM);
    if (tid < 64){
      bool ok;
      do {
        ok = true;
        #pragma unroll
        for (int s=0;s<4;++s){
          unsigned v = __hip_atomic_load(flg + (size_t)(tid + (s<<6))*32,
                                         __ATOMIC_RELAXED, __HIP_MEMORY_SCOPE_SYSTEM);
          ok = ok && (v >= ep);
        }
        if (!__all(ok)) __builtin_amdgcn_s_sleep(1);
      } while (!__all(ok));
      if (tid < 16)
        __hip_atomic_store(rel + (size_t)tid*32, ep,
                           __ATOMIC_RELAXED, __HIP_MEMORY_SCOPE_SYSTEM);
    }
  } else {
    if (tid == 0){
      __hip_atomic_store(flg + (size_t)bid*32, ep,
                         __ATOMIC_RELAXED, __HIP_MEMORY_SCOPE_SYSTEM);
      unsigned* myrel = rel + (size_t)(bid>>4)*32;
      while (__hip_atomic_load(myrel, __ATOMIC_RELAXED, __HIP_MEMORY_SCOPE_SYSTEM) < ep)
        __builtin_amdgcn_s_sleep(2);
    }
  }
  __syncthreads();
}

// skinny GEMM: 32 cols x 16 batches, in-block 8-way ksplit. sx: LDS [k][20].
DEV void sgemm_core(float* sred, const float* sx, const float* __restrict__ W,
                    int ldw, int colx, int kn)
{
  const int tid = threadIdx.x;
  const int ks  = tid >> 5;
  const int k0  = ks * kn;
  float acc[16];
  #pragma unroll
  for (int i=0;i<16;++i) acc[i]=0.f;
  const float* wp = W + (size_t)k0*ldw + colx;
  const float* xp = sx + k0*20;
  #pragma unroll 4
  for (int k=0;k<kn;++k){
    float w = *wp; wp += ldw;
    float4 x0 = *(const float4*)(xp);
    float4 x1 = *(const float4*)(xp+4);
    float4 x2 = *(const float4*)(xp+8);
    float4 x3 = *(const float4*)(xp+12);
    xp += 20;
    acc[0]=fmaf(w,x0.x,acc[0]);  acc[1]=fmaf(w,x0.y,acc[1]);
    acc[2]=fmaf(w,x0.z,acc[2]);  acc[3]=fmaf(w,x0.w,acc[3]);
    acc[4]=fmaf(w,x1.x,acc[4]);  acc[5]=fmaf(w,x1.y,acc[5]);
    acc[6]=fmaf(w,x1.z,acc[6]);  acc[7]=fmaf(w,x1.w,acc[7]);
    acc[8]=fmaf(w,x2.x,acc[8]);  acc[9]=fmaf(w,x2.y,acc[9]);
    acc[10]=fmaf(w,x2.z,acc[10]); acc[11]=fmaf(w,x2.w,acc[11]);
    acc[12]=fmaf(w,x3.x,acc[12]); acc[13]=fmaf(w,x3.y,acc[13]);
    acc[14]=fmaf(w,x3.z,acc[14]); acc[15]=fmaf(w,x3.w,acc[15]);
  }
  const int col = tid & 31;
  #pragma unroll
  for (int b=0;b<16;++b) sred[ks*512 + b*32 + col] = acc[b];
}

#define SRED8(o) (sred[(o)]+sred[512+(o)]+sred[1024+(o)]+sred[1536+(o)]+ \
                  sred[2048+(o)]+sred[2560+(o)]+sred[3072+(o)]+sred[3584+(o)])

DEV void stage_x264(float* sx, const float* __restrict__ xin, int tt){
  // 16 x 264 floats as float4 (264 = 66*4, rows 1056B = 16B-aligned)
  for (int e=threadIdx.x; e<1056; e+=NT){
    int b = e/66, k4 = e - b*66;
    float4 v = *(const float4*)(xin + ((size_t)(b*256+tt))*264 + 4*k4);
    float* d = sx + (4*k4)*20 + b;
    d[0]=v.x; d[20]=v.y; d[40]=v.z; d[60]=v.w;
  }
}
DEV void stage_h_sys(float* sx, const float* h){
  // 16x512 floats = 4096 f2
  #pragma unroll
  for (int i=0;i<16;++i){
    int e = threadIdx.x + (i<<8);
    int b = e>>8, k2 = e&255;
    float2 v = ld2_sys(h + (b<<9) + (k2<<1));
    float* d = sx + (k2*2)*20 + b;
    d[0]=v.x; d[20]=v.y;
  }
}
DEV void stage_rv_sys(float* sx, const float* rv){
  // 16x256 floats = 2048 f2
  #pragma unroll
  for (int i=0;i<8;++i){
    int e = threadIdx.x + (i<<8);
    int b = e>>7, k2 = e&127;
    float2 v = ld2_sys(rv + (b<<8) + (k2<<1));
    float* d = sx + (k2*2)*20 + b;
    d[0]=v.x; d[20]=v.y;
  }
}

__global__ void k_zero(float* __restrict__ ws){
  size_t i = (size_t)blockIdx.x*blockDim.x + threadIdx.x;
  size_t st = (size_t)gridDim.x*blockDim.x;
  for (; i<WS_TOTAL; i+=st) ws[i]=0.0f;
}

__global__ __launch_bounds__(NT, 2) void k_dnc(
    const float* __restrict__ xin, const float* __restrict__ Wx,
    const float* __restrict__ Wh,  const float* __restrict__ bl,
    const float* __restrict__ Wxi, const float* __restrict__ bxi,
    const float* __restrict__ Wy,  const float* __restrict__ Wr,
    const float* __restrict__ by,  float* __restrict__ out,
    float* __restrict__ ws)
{
  __shared__ float smem[14336];
  float* sx   = smem;
  float* sred = smem + 10240;
  const int tid  = threadIdx.x;
  const int bid  = blockIdx.x;
  const int lane = tid & 63, wv = tid >> 6;
  const int half = lane >> 5, l32 = lane & 31;
  unsigned* flg = (unsigned*)(ws + OFF_FLG);
  unsigned* rel = (unsigned*)(ws + OFF_REL);
  unsigned ep = 0;

  // ---- prologue: gates-x(0) -> GPA (zeroed by k_zero; h0=rv0=0) ----
  if (bid < 64){
    stage_x264(sx, xin, 0);
    __syncthreads();
    sgemm_core(sred, sx, Wx, 2048, (bid<<5)+(tid&31), 33);
    __syncthreads();
    for (int o=tid;o<512;o+=NT){
      int b=o>>5, c=o&31;
      atomicAdd(ws + OFF_GPA + (size_t)(b<<11) + (bid<<5) + c, SRED8(o));
    }
  }
  ep++; gbar(flg, rel, ep, bid);

  for (int t=0; t<S_; ++t){
    float* gp_cur = ws + ((t&1) ? OFF_GPB : OFF_GPA);
    float* gp_nxt = ws + ((t&1) ? OFF_GPA : OFF_GPB);
    // ========== phase B1: LSTM cell (16 batch-blocks) | zero GP_nxt ==========
    if (bid < 16){
      int b = bid;
      const float* gp = gp_cur + (b<<11);
      int j2 = tid<<1;
      float2 gi = ld2_sys(gp + j2);
      float2 gf = ld2_sys(gp + 512 + j2);
      float2 gg = ld2_sys(gp + 1024 + j2);
      float2 go = ld2_sys(gp + 1536 + j2);
      float2 bi = *(const float2*)(bl + j2);
      float2 bf = *(const float2*)(bl + 512 + j2);
      float2 bg = *(const float2*)(bl + 1024 + j2);
      float2 bo = *(const float2*)(bl + 1536 + j2);
      float* cb = ws + OFF_C + (b<<9) + j2;       // private to this block
      float2 cc = *(float2*)cb;
      float2 cn, hn;
      cn.x = sigm(gf.x+bf.x)*cc.x + sigm(gi.x+bi.x)*tanhf(gg.x+bg.x);
      cn.y = sigm(gf.y+bf.y)*cc.y + sigm(gi.y+bi.y)*tanhf(gg.y+bg.y);
      hn.x = sigm(go.x+bo.x)*tanhf(cn.x);
      hn.y = sigm(go.y+bo.y)*tanhf(cn.y);
      *(float2*)cb = cn;
      st2_sys(ws + OFF_H + (b<<9) + j2, hn);
    } else if (bid < 32){
      int b = bid-16;
      float2 z; z.x=0.f; z.y=0.f;
      #pragma unroll
      for (int i=0;i<4;++i)
        st2_sys(gp_nxt + (size_t)(b<<11) + ((tid + (i<<8))<<1), z);
    }
    ep++; gbar(flg, rel, ep, bid);

    // ========== phase B2: xi | yh | gates-h(t+1) (all stage h once) ==========
    if (bid < 15){
      stage_h_sys(sx, ws+OFF_H);
      __syncthreads();
      int cbase = bid<<5;
      int cc = cbase + (tid&31);
      sgemm_core(sred, sx, Wxi, 471, (cc<471?cc:470), 64);
      __syncthreads();
      for (int o=tid;o<512;o+=NT){
        int b=o>>5, c=o&31; int col=cbase+c;
        if (col<471) st_sys(ws + OFF_XI + (size_t)b*480 + col, SRED8(o) + bxi[col]);
      }
    } else if (bid < 23){
      stage_h_sys(sx, ws+OFF_H);
      __syncthreads();
      int cbase = (bid-15)<<5;
      sgemm_core(sred, sx, Wy, 256, cbase+(tid&31), 64);
      __syncthreads();
      for (int o=tid;o<512;o+=NT){
        int b=o>>5, c=o&31;
        st_sys(ws + OFF_YH + (b<<8) + cbase + c, SRED8(o) + by[cbase+c]);
      }
    } else if (bid < 87){
      if (t < 255){
        stage_h_sys(sx, ws+OFF_H);
        __syncthreads();
        int cbase = (bid-23)<<5;
        sgemm_core(sred, sx, Wh, 2048, cbase+(tid&31), 64);
        __syncthreads();
        for (int o=tid;o<512;o+=NT){
          int b=o>>5, c=o&31;
          atomicAdd(gp_nxt + (size_t)(b<<11) + cbase + c, SRED8(o));
        }
      }
    }
    ep++; gbar(flg, rel, ep, bid);

    // ===== phase C: ctrl(0..15) | content(32..47, XCD-pinned) | gates-x(48..111) =====
    if (bid < 16){
      int b = bid;
      float* xv = smem; float* uu = smem+512; float* sa = smem+768; float* sb = smem+1024; float* red = smem+1280;
      if (tid < 240){
        float2 v = ld2_sys(ws + OFF_XI + (size_t)b*480 + (tid<<1));
        xv[tid<<1]=v.x; xv[(tid<<1)+1]=v.y;
      }
      __syncthreads();
      int n = tid;
      float f0=sigm(xv[453]), f1=sigm(xv[454]), f2v=sigm(xv[455]), f3=sigm(xv[456]);
      const float* wrb = ws+OFF_WR+(size_t)(b<<10);
      float psi=(1.f-f0*ld_sys(wrb+n))*(1.f-f1*ld_sys(wrb+256+n))
               *(1.f-f2v*ld_sys(wrb+512+n))*(1.f-f3*ld_sys(wrb+768+n));
      float uo=ws[OFF_USG+(b<<8)+n];            // private cached
      float wwp=ld_sys(ws+OFF_WW+(b<<8)+n);
      float un=(uo+wwp-uo*wwp)*psi;
      uu[n]=un; ws[OFF_USG+(b<<8)+n]=un;
      __syncthreads();
      int rk=0;
      #pragma unroll 8
      for (int j=0;j<256;++j){
        float uj=uu[j];
        rk += (uj<un)||(uj==un && j<n);
      }
      sa[rk]=un;
      __syncthreads();
      float* cur=sa; float* nxt=sb;
      for (int off=1;off<256;off<<=1){
        float v=cur[n]; if (n>=off) v*=cur[n-off];
        nxt[n]=v;
        __syncthreads();
        float* tmp=cur; cur=nxt; nxt=tmp;
      }
      float pe = rk ? cur[rk-1] : 1.f;
      float al = (1.f-un)*pe;
      st_sys(ws+OFF_ALC+(b<<8)+n, al);
      float sumA = bredsum(al, red);
      if (tid==0){
        st_sys(ws+OFF_SCL+b*4+0, sigm(xv[457]));
        st_sys(ws+OFF_SCL+b*4+1, sigm(xv[458]));
        st_sys(ws+OFF_SCL+b*4+2, sumA);
      }
      {
        int r=tid>>6, m=tid&63;
        float kv=xv[(r<<6)+m];
        float s2=wredsum(kv*kv);
        float br=oneplus_(xv[256+r]);
        st_agt(ws+OFF_KNR+(b<<8)+tid, kv*br/(sqrtf(s2)+1e-6f));
      }
      if (tid<4){
        float p0=xv[459+tid*3], p1=xv[460+tid*3], p2=xv[461+tid*3];
        float mx=fmaxf(p0,fmaxf(p1,p2));
        float e0=expf(p0-mx), e1=expf(p1-mx), e2=expf(p2-mx);
        float s=e0+e1+e2;
        st_agt(ws+OFF_PI+b*16+tid*3+0, e0/s);
        st_agt(ws+OFF_PI+b*16+tid*3+1, e1/s);
        st_agt(ws+OFF_PI+b*16+tid*3+2, e2/s);
      }
      if (tid<64){
        st_agt(ws+OFF_ERS+(b<<6)+tid, sigm(xv[325+tid]));
        st_agt(ws+OFF_WVC+(b<<6)+tid, xv[389+tid]);
      }
      float* bw=ws+OFF_BWD+(size_t)(b<<10);
      float2 z; z.x=0.f; z.y=0.f;
      st2_sys(bw + (tid<<1), z);
      st2_sys(bw + 512 + (tid<<1), z);
    } else if (bid >= 32 && bid < 48){
      int b = bid-32;   // (32+b)%8 == b%8: same XCD as mem writer
      float* knw=smem; float* sims=smem+64; float* red=smem+320;
      if (wv==0){
        float kv=ld_sys(ws+OFF_XI+(size_t)b*480+260+lane);
        float s2=wredsum(kv*kv);
        float bw_=oneplus_(ld_sys(ws+OFF_XI+(size_t)b*480+324));
        knw[lane]=kv*bw_/(sqrtf(s2)+1e-6f);
      }
      __syncthreads();
      const float* memb=ws+OFF_MEM+(size_t)b*16384;
      for (int i=0;i<32;++i){
        int n=(wv<<6)+(i<<1)+half;
        float2 v=ld2_agt(memb+(n<<6)+(l32<<1));
        float d=hredsum32(v.x*knw[l32<<1]+v.y*knw[(l32<<1)+1]);
        if (l32==0) sims[n]=d/(sqrtf(ld_agt(ws+OFF_NRM+(b<<8)+n))+1e-6f);
      }
      __syncthreads();
      float s=sims[tid];
      float mx=bredmax(s,red); float e=expf(s-mx); float sm=bredsum(e,red);
      st_sys(ws+OFF_CW+(b<<8)+tid, e/sm);
    } else if (bid >= 48 && bid < 112){
      if (t < 255){
        stage_x264(sx, xin, t+1);
        __syncthreads();
        int cbase = (bid-48)<<5;
        sgemm_core(sred, sx, Wx, 2048, cbase+(tid&31), 33);
        __syncthreads();
        for (int o=tid;o<512;o+=NT){
          int b=o>>5, c=o&31;
          atomicAdd(gp_nxt + (size_t)(b<<11) + cbase + c, SRED8(o));
        }
      }
    }
    ep++; gbar(flg, rel, ep, bid);

    // ========== phase D: link+fwd/bwd (0..127) | mem update (128..143, pinned) ==========
    if (bid < 128){
      int b=bid>>3, rc=bid&7;
      float* wwi=smem; float* wrl=smem+32; float* fpart=smem+160;
      float ga=ld_sys(ws+OFF_SCL+b*4), gw=ld_sys(ws+OFF_SCL+b*4+1);
      int j=tid;
      float wj=gw*(ga*ld_sys(ws+OFF_ALC+(b<<8)+j)+(1.f-ga)*ld_sys(ws+OFF_CW+(b<<8)+j));
      float pj=ld_sys(ws+OFF_PRC+(size_t)(t&1)*4096+(b<<8)+j);
      const float* wrb=ws+OFF_WR+(size_t)(b<<10);
      float wr0=ld_sys(wrb+j), wr1=ld_sys(wrb+256+j),
            wr2=ld_sys(wrb+512+j), wr3=ld_sys(wrb+768+j);
      if (tid<32){
        int i=(rc<<5)+tid;
        wwi[tid]=gw*(ga*ld_sys(ws+OFF_ALC+(b<<8)+i)+(1.f-ga)*ld_sys(ws+OFF_CW+(b<<8)+i));
      }
      if (tid<128) wrl[(tid>>5)*32+(tid&31)] = ld_sys(wrb+((tid>>5)<<8)+(rc<<5)+(tid&31));
      __syncthreads();
      float b0=0.f,b1=0.f,b2=0.f,b3=0.f;
      float* lrow=ws+OFF_LNK+(size_t)b*65536+(size_t)(rc<<5)*256;  // private: plain cached
      for (int il=0;il<32;++il){
        int i=(rc<<5)+il;
        float Lo=lrow[il*256+j];
        float wi=wwi[il];
        float Ln=(1.f-wi-wj)*Lo + wi*pj;
        if (i==j) Ln=0.f;
        lrow[il*256+j]=Ln;
        float s0=wredsum(Ln*wr0), s1=wredsum(Ln*wr1), s2=wredsum(Ln*wr2), s3=wredsum(Ln*wr3);
        if (lane==0){
          fpart[wv*128+il]=s0; fpart[wv*128+32+il]=s1;
          fpart[wv*128+64+il]=s2; fpart[wv*128+96+il]=s3;
        }
        b0=fmaf(Ln,wrl[il],b0); b1=fmaf(Ln,wrl[32+il],b1);
        b2=fmaf(Ln,wrl[64+il],b2); b3=fmaf(Ln,wrl[96+il],b3);
      }
      __syncthreads();
      if (tid<128){
        int r=tid>>5, il=tid&31;
        float s=fpart[r*32+il]+fpart[128+r*32+il]+fpart[256+r*32+il]+fpart[384+r*32+il];
        st_sys(ws+OFF_FWD+(size_t)(b<<10)+(r<<8)+(rc<<5)+il, s);
      }
      float* bwd=ws+OFF_BWD+(size_t)(b<<10);
      atomicAdd(&bwd[j],b0); atomicAdd(&bwd[256+j],b1);
      atomicAdd(&bwd[512+j],b2); atomicAdd(&bwd[768+j],b3);
    } else if (bid < 144){
      int b=bid-128;   // (128+b)%8 == b%8
      float ga=ld_sys(ws+OFF_SCL+b*4), gw=ld_sys(ws+OFF_SCL+b*4+1), sA=ld_sys(ws+OFF_SCL+b*4+2);
      float sww=gw*(ga*sA+(1.f-ga));
      float2 er = ld2_agt(ws+OFF_ERS+(b<<6)+(l32<<1));
      float2 wvv= ld2_agt(ws+OFF_WVC+(b<<6)+(l32<<1));
      float* memb=ws+OFF_MEM+(size_t)b*16384;
      for (int i=0;i<32;++i){
        int n=(wv<<6)+(i<<1)+half;
        float wwn=gw*(ga*ld_sys(ws+OFF_ALC+(b<<8)+n)+(1.f-ga)*ld_sys(ws+OFF_CW+(b<<8)+n));
        float2 v=ld2_agt(memb+(n<<6)+(l32<<1));
        v.x=v.x*(1.f-wwn*er.x)+wwn*wvv.x;
        v.y=v.y*(1.f-wwn*er.y)+wwn*wvv.y;
        st2_agt(memb+(n<<6)+(l32<<1), v);
        float s2=hredsum32(v.x*v.x+v.y*v.y);
        if (l32==0){
          st_agt(ws+OFF_NRM+(b<<8)+n, s2);
          st_sys(ws+OFF_WW +(b<<8)+n, wwn);
          float po=ld_sys(ws+OFF_PRC+(size_t)(t&1)*4096+(b<<8)+n);
          st_sys(ws+OFF_PRC+(size_t)((t+1)&1)*4096+(b<<8)+n, (1.f-sww)*po+wwn);
        }
      }
    }
    ep++; gbar(flg, rel, ep, bid);

    // ========== phase E: read heads (64 blocks, XCD-pinned, mem cached in regs) ==========
    if (bid < 64){
      int x=bid&7, r=(bid>>3)&3, u=bid>>5;
      int b = x + (u<<3);          // bid%8 == b%8
      float* knl=smem; float* sims=smem+64; float* wrs=smem+320; float* pt=smem+576; float* red=smem+1088;
      if (wv==0) knl[lane]=ld_agt(ws+OFF_KNR+(b<<8)+(r<<6)+lane);
      __syncthreads();
      const float* memb=ws+OFF_MEM+(size_t)b*16384;
      float2 mv[32];
      #pragma unroll 4
      for (int i=0;i<32;++i){
        int n=(wv<<6)+(i<<1)+half;
        float2 v=ld2_agt(memb+(n<<6)+(l32<<1));
        mv[i]=v;
        float d=hredsum32(v.x*knl[l32<<1]+v.y*knl[(l32<<1)+1]);
        if (l32==0) sims[n]=d/(sqrtf(ld_agt(ws+OFF_NRM+(b<<8)+n))+1e-6f);
      }
      __syncthreads();
      float s=sims[tid];
      float mx=bredmax(s,red); float e=expf(s-mx); float sm=bredsum(e,red);
      float cr=e/sm;
      float p0=ld_agt(ws+OFF_PI+b*16+r*3), p1=ld_agt(ws+OFF_PI+b*16+r*3+1), p2=ld_agt(ws+OFF_PI+b*16+r*3+2);
      float wr=p0*ld_sys(ws+OFF_BWD+(size_t)(b<<10)+(r<<8)+tid) + p1*cr
             + p2*ld_sys(ws+OFF_FWD+(size_t)(b<<10)+(r<<8)+tid);
      st_sys(ws+OFF_WR+(size_t)(b<<10)+(r<<8)+tid, wr);
      wrs[tid]=wr;
      __syncthreads();
      float ax=0.f, ay=0.f;
      #pragma unroll 4
      for (int i=0;i<32;++i){
        int n=(wv<<6)+(i<<1)+half;
        float w=wrs[n];
        ax=fmaf(w,mv[i].x,ax); ay=fmaf(w,mv[i].y,ay);
      }
      int slot=(wv<<1)+half;
      pt[slot*64+(l32<<1)]=ax; pt[slot*64+(l32<<1)+1]=ay;
      __syncthreads();
      if (tid<64){
        float sm2=0.f;
        #pragma unroll
        for (int s2=0;s2<8;++s2) sm2+=pt[s2*64+tid];
        st_sys(ws+OFF_RV+(b<<8)+(r<<6)+tid, sm2);
      }
    }
    ep++; gbar(flg, rel, ep, bid);

    // ========== phase A': gates-rv(t+1) (0..63) | y output (64..71) ==========
    if (bid < 64){
      if (t < 255){
        stage_rv_sys(sx, ws+OFF_RV);
        __syncthreads();
        sgemm_core(sred, sx, Wx+(size_t)264*2048, 2048, (bid<<5)+(tid&31), 32);
        __syncthreads();
        for (int o=tid;o<512;o+=NT){
          int b=o>>5, c=o&31;
          atomicAdd(gp_nxt + (size_t)(b<<11) + (bid<<5) + c, SRED8(o));
        }
      }
    } else if (bid < 72){
      stage_rv_sys(sx, ws+OFF_RV);
      __syncthreads();
      int cbase=(bid-64)<<5;
      sgemm_core(sred, sx, Wr, 256, cbase+(tid&31), 32);
      __syncthreads();
      for (int o=tid;o<512;o+=NT){
        int b=o>>5, c=o&31;
        out[((size_t)((b<<8)+t)<<8)+cbase+c] = ld_sys(ws+OFF_YH+(b<<8)+cbase+c) + SRED8(o);
      }
    }
    ep++; gbar(flg, rel, ep, bid);
  }
}

extern "C" void kernel_launch(void* const* d_in, const int* in_sizes, int n_in,
                              void* d_out, int out_size, void* d_ws, size_t ws_size,
                              hipStream_t stream) {
  (void)in_sizes; (void)out_size;
  if (n_in < 9) return;
  const float* xin = (const float*)d_in[0];
  const float* Wx  = (const float*)d_in[1];
  const float* Wh  = (const float*)d_in[2];
  const float* bl  = (const float*)d_in[3];
  const float* Wxi = (const float*)d_in[4];
  const float* bxi = (const float*)d_in[5];
  const float* Wy  = (const float*)d_in[6];
  const float* Wr  = (const float*)d_in[7];
  const float* by  = (const float*)d_in[8];
  float* out = (float*)d_out;
  float* ws  = (float*)d_ws;
  if (ws_size < WS_TOTAL*sizeof(float)) return;

  hipLaunchKernelGGL(k_zero, dim3(512), dim3(256), 0, stream, ws);
  hipLaunchKernelGGL(k_dnc, dim3(NB), dim3(NT), 0, stream,
                     xin, Wx, Wh, bl, Wxi, bxi, Wy, Wr, by, out, ws);
}